// Round 17
// baseline (80.016 us; speedup 1.0000x reference)
//
#include <hip/hip_runtime.h>
#include <hip/hip_bf16.h>

typedef __attribute__((ext_vector_type(4))) float f32x4;
typedef __attribute__((ext_vector_type(8))) short bf16x8;

#define M_TOT 30752   // 8*62*62 output pixels

__device__ __forceinline__ unsigned short f2bf(float f) {
  unsigned int u = __float_as_uint(f);
  u = u + 0x7FFF + ((u >> 16) & 1);   // round-to-nearest-even
  return (unsigned short)(u >> 16);
}

__device__ __forceinline__ void gload16(const void* g, void* l) {
  __builtin_amdgcn_global_load_lds((const __attribute__((address_space(1))) unsigned int*)g,
                                   (__attribute__((address_space(3))) unsigned int*)l,
                                   16, 0, 0);
}

// ---- fused prep: blocks 0..575 = keff+k2t (latency-bound, hides under cast);
//                  blocks 576..4671 = cast x->bf16 (HBM-bound, fills machine).
__global__ __launch_bounds__(256) void fused_k(const float* __restrict__ x,
                                               const float* __restrict__ P,
                                               const float* __restrict__ Q,
                                               const float* __restrict__ S,
                                               unsigned short* __restrict__ xb,
                                               unsigned short* __restrict__ K2t) {
  __shared__ float ldsK[256 * 4];
  const int bid = blockIdx.x;
  const int t = threadIdx.x;

  if (bid >= 576) {                  // ---- cast x -> bf16 ----
    int i = (bid - 576) * 256 + t;
    const f32x4* xp = (const f32x4*)x;
    f32x4 a = xp[2 * i];
    f32x4 b = xp[2 * i + 1];
    bf16x8 o;
    o[0] = (short)f2bf(a[0]); o[1] = (short)f2bf(a[1]);
    o[2] = (short)f2bf(a[2]); o[3] = (short)f2bf(a[3]);
    o[4] = (short)f2bf(b[0]); o[5] = (short)f2bf(b[1]);
    o[6] = (short)f2bf(b[2]); o[7] = (short)f2bf(b[3]);
    ((bf16x8*)xb)[i] = o;
    return;
  }

  const int kk = bid / 64;           // 0..8
  const int f0 = (bid & 63) * 4;     // 0..252
  {                                  // phase 1: Keff slice -> LDS (thread = o)
    float k0 = 0.f, k1 = 0.f, k2 = 0.f, k3 = 0.f;
    const float* qp = Q + t * 144 + kk * 16;
    const float* sp = S + (t >> 4) * 4096 + (t & 15) * 256 + f0;
#pragma unroll
    for (int bi = 0; bi < 16; ++bi) {
      float qv = qp[bi];
      const float* s4 = sp + bi * 65536;
      k0 = fmaf(qv, s4[0], k0); k1 = fmaf(qv, s4[1], k1);
      k2 = fmaf(qv, s4[2], k2); k3 = fmaf(qv, s4[3], k3);
    }
    ldsK[t * 4 + 0] = k0; ldsK[t * 4 + 1] = k1;
    ldsK[t * 4 + 2] = k2; ldsK[t * 4 + 3] = k3;
  }
  __syncthreads();
  {                                  // phase 2: contraction over o (thread = ci)
    const int ci = t;
    float acc[4] = {0.f, 0.f, 0.f, 0.f};
#pragma unroll 8
    for (int o = 0; o < 256; ++o) {
      float pv = P[o * 256 + ci];    // coalesced; ldsK broadcast
      acc[0] = fmaf(pv, ldsK[o * 4 + 0], acc[0]);
      acc[1] = fmaf(pv, ldsK[o * 4 + 1], acc[1]);
      acc[2] = fmaf(pv, ldsK[o * 4 + 2], acc[2]);
      acc[3] = fmaf(pv, ldsK[o * 4 + 3], acc[3]);
    }
#pragma unroll
    for (int j = 0; j < 4; ++j)
      K2t[kk * 65536 + (f0 + j) * 256 + ci] = f2bf(acc[j]);
  }
}

// ---- main: implicit-GEMM conv.  M=30752, N=256, K=2304.
// BM=128, BN=128, BK=64/step; 256 thr = 4 waves (sk x wn), wave 128x64 over
// its K-half. T3+T4 minimum-2-phase ring (catalog recipe, exact):
//   step t: STAGE(t+1, buf^1)  ->  ds_read+MFMA(buf)  ->  vmcnt(0)+barrier
// ONE barrier/step, wait AFTER compute: the vmcnt lands ~900cy after the
// stage issue (L2 ~300cy already paid); the barrier doubles as the
// read-before-overwrite fence for buf^1's next refill. Double-buffer 64KB
// -> 2 blocks/CU. Conflict-free 64B-row swizzle (measured 0). Grid 488 =
// 8 XCD x 61: (nt=0,1) pair shares A-tile within one XCD L2.
__global__ __launch_bounds__(256, 2) void conv_gemm(const unsigned short* __restrict__ xb,
                                                    const unsigned short* __restrict__ K2t,
                                                    float* __restrict__ out) {
  __shared__ __attribute__((aligned(16))) char smem[65536];  // 2 x (A16K + B16K)

  const int tid = threadIdx.x;
  const int lane = tid & 63;
  const int wid = tid >> 6;         // 0..3
  const int sk = wid >> 1;          // k-half
  const int wn = wid & 1;           // n-half

  const int wgid = (blockIdx.x & 7) * 61 + (blockIdx.x >> 3);
  if (wgid >= 482) return;
  const int mt = wgid >> 1;         // 0..240
  const int nt = wgid & 1;
  const int m0 = mt * 128;
  const int n0 = nt * 128;

  const int rl = lane & 15;
  const int kg = lane >> 4;

  // staging: thread t owns chunks {t, t+256, t+512, t+768}; source slot
  // pre-swizzled s_src = (t&3) ^ ((t>>3)&3)  [row = t>>2]
  const int s_src = ((tid & 3) ^ ((tid >> 3) & 3)) * 8;   // element offset
  int gA0, gA1;
  {
    int m = m0 + (tid >> 2); if (m >= M_TOT) m = M_TOT - 1;
    int b = m / 3844; int rem = m - b * 3844;
    int h = rem / 62; int w = rem - h * 62;
    gA0 = ((b * 64 + h) * 64 + w) * 256 + s_src;
    m = m0 + (tid >> 2) + 64; if (m >= M_TOT) m = M_TOT - 1;
    b = m / 3844; rem = m - b * 3844;
    h = rem / 62; w = rem - h * 62;
    gA1 = ((b * 64 + h) * 64 + w) * 256 + s_src;
  }
  const int fB0 = (n0 + (tid >> 2)) * 256 + s_src;        // B rows f, f+64
  const int fB1 = (n0 + (tid >> 2) + 64) * 256 + s_src;

  f32x4 zero = {0.f, 0.f, 0.f, 0.f};
  f32x4 acc[8][4];
#pragma unroll
  for (int i = 0; i < 8; ++i)
#pragma unroll
    for (int j = 0; j < 4; ++j) acc[i][j] = zero;

  // read-side: slot = kg ^ ((rl>>1)&3); mi/ni stride 16 rows = 1024B
  const int slotr = (kg ^ ((rl >> 1) & 3)) * 16;              // bytes
  const int aoff = sk * 8192 + rl * 64 + slotr;               // A region bytes
  const int boff = 16384 + sk * 8192 + (wn * 64 + rl) * 64 + slotr;  // B region

#define STAGE(t, base)                                                         \
  {                                                                            \
    int kk_ = (t) >> 2, cb_ = (t) & 3;                                         \
    int kh_ = kk_ / 3, kw_ = kk_ - kh_ * 3;                                    \
    int offA_ = kh_ * 16384 + kw_ * 256 + cb_ * 64;                            \
    int offB_ = kk_ * 65536 + cb_ * 64;                                        \
    unsigned short* bA = (unsigned short*)(base);                              \
    unsigned short* bB = (unsigned short*)((char*)(base) + 16384);             \
    gload16(xb + gA0 + offA_,      bA + tid * 8);                              \
    gload16(xb + gA1 + offA_,      bA + (tid + 256) * 8);                      \
    gload16(xb + gA0 + offA_ + 32, bA + (tid + 512) * 8);                      \
    gload16(xb + gA1 + offA_ + 32, bA + (tid + 768) * 8);                      \
    gload16(K2t + offB_ + fB0,      bB + tid * 8);                             \
    gload16(K2t + offB_ + fB1,      bB + (tid + 256) * 8);                     \
    gload16(K2t + offB_ + fB0 + 32, bB + (tid + 512) * 8);                     \
    gload16(K2t + offB_ + fB1 + 32, bB + (tid + 768) * 8);                     \
  }

  // prologue: stage tile 0, drain, sync
  STAGE(0, smem);
  asm volatile("s_waitcnt vmcnt(0)" ::: "memory");
  __builtin_amdgcn_sched_barrier(0);
  __builtin_amdgcn_s_barrier();
  __builtin_amdgcn_sched_barrier(0);

  for (int t = 0; t < 36; ++t) {
    char* cur = smem + (t & 1) * 32768;

    // 1) issue next tile's stage FIRST (hides under this step's compute)
    if (t < 35) STAGE(t + 1, smem + ((t + 1) & 1) * 32768);
    __builtin_amdgcn_sched_barrier(0);

    // 2) ds_read + MFMA on current tile (compiler emits counted lgkmcnt)
    bf16x8 bfr[4];
#pragma unroll
    for (int ni = 0; ni < 4; ++ni)
      bfr[ni] = *(const bf16x8*)(cur + boff + ni * 1024);
    bf16x8 a0 = *(const bf16x8*)(cur + aoff);
    bf16x8 a1 = *(const bf16x8*)(cur + aoff + 1024);
#pragma unroll
    for (int j = 0; j < 4; ++j) {
      bf16x8 a2, a3;
      if (j < 3) {
        a2 = *(const bf16x8*)(cur + aoff + (2 * j + 2) * 1024);
        a3 = *(const bf16x8*)(cur + aoff + (2 * j + 3) * 1024);
      }
      __builtin_amdgcn_s_setprio(1);
#pragma unroll
      for (int ni = 0; ni < 4; ++ni)
        acc[2 * j][ni] = __builtin_amdgcn_mfma_f32_16x16x32_bf16(
            a0, bfr[ni], acc[2 * j][ni], 0, 0, 0);
#pragma unroll
      for (int ni = 0; ni < 4; ++ni)
        acc[2 * j + 1][ni] = __builtin_amdgcn_mfma_f32_16x16x32_bf16(
            a1, bfr[ni], acc[2 * j + 1][ni], 0, 0, 0);
      __builtin_amdgcn_s_setprio(0);
      a0 = a2; a1 = a3;
    }

    // 3) wait AFTER compute: stage(t+1) issued ~900cy ago -> latency paid.
    //    Single barrier: tile t+1 visible AND buf[cur] safe to refill at t+1.
    if (t < 35) {
      __builtin_amdgcn_sched_barrier(0);
      asm volatile("s_waitcnt vmcnt(0)" ::: "memory");
      __builtin_amdgcn_sched_barrier(0);
      __builtin_amdgcn_s_barrier();
      __builtin_amdgcn_sched_barrier(0);
    }
  }

  __syncthreads();   // main loop done; smem reused as reduction buffer

  // epilogue: sk=1 waves stage acc in LDS (64KB exactly); sk=0 adds + stores.
  // D row = kg*4 + r (+16*mi), col = rl (+16*ni +64*wn).
  float* red = (float*)smem;
  if (sk == 1) {
#pragma unroll
    for (int mi = 0; mi < 8; ++mi)
#pragma unroll
      for (int ni = 0; ni < 4; ++ni)
        *(f32x4*)((char*)red + (((wn * 8 + mi) * 4 + ni) * 64 + lane) * 16) =
            acc[mi][ni];
  }
  __syncthreads();
  if (sk == 0) {
#pragma unroll
    for (int mi = 0; mi < 8; ++mi) {
      int mb = m0 + mi * 16 + kg * 4;
#pragma unroll
      for (int ni = 0; ni < 4; ++ni) {
        f32x4 o = *(f32x4*)((char*)red + (((wn * 8 + mi) * 4 + ni) * 64 + lane) * 16);
        o += acc[mi][ni];
        int f = n0 + wn * 64 + ni * 16 + rl;
#pragma unroll
        for (int r = 0; r < 4; ++r) {
          int m = mb + r;
          if (m < M_TOT) out[m * 256 + f] = o[r];
        }
      }
    }
  }
#undef STAGE
}

extern "C" void kernel_launch(void* const* d_in, const int* in_sizes, int n_in,
                              void* d_out, int out_size, void* d_ws, size_t ws_size,
                              hipStream_t stream) {
  const float* x = (const float*)d_in[0];   // [8,64,64,256]
  const float* P = (const float*)d_in[1];   // [256,256]
  const float* Q = (const float*)d_in[2];   // [256,3,3,16]
  const float* S = (const float*)d_in[3];   // [256,16,256]
  float* out = (float*)d_out;               // [8,62,62,256]

  char* ws = (char*)d_ws;
  unsigned short* xb  = (unsigned short*)ws;               // 16,777,216 B
  unsigned short* K2t = (unsigned short*)(ws + 16777216);  //  1,179,648 B

  fused_k<<<4672, 256, 0, stream>>>(x, P, Q, S, xb, K2t);
  conv_gemm<<<488, 256, 0, stream>>>(xb, K2t, out);
}

// Round 19
// 76.853 us; speedup vs baseline: 1.0412x; 1.0412x over previous
//
#include <hip/hip_runtime.h>
#include <hip/hip_bf16.h>

typedef __attribute__((ext_vector_type(4))) float f32x4;
typedef __attribute__((ext_vector_type(8))) short bf16x8;

#define M_TOT 30752   // 8*62*62 output pixels

__device__ __forceinline__ unsigned short f2bf(float f) {
  unsigned int u = __float_as_uint(f);
  u = u + 0x7FFF + ((u >> 16) & 1);   // round-to-nearest-even
  return (unsigned short)(u >> 16);
}

__device__ __forceinline__ void gload16(const void* g, void* l) {
  __builtin_amdgcn_global_load_lds((const __attribute__((address_space(1))) unsigned int*)g,
                                   (__attribute__((address_space(3))) unsigned int*)l,
                                   16, 0, 0);
}

// ---- fused prep: blocks 0..575 = keff+k2t (hides under cast);
//                  blocks 576..4671 = cast x->bf16 (HBM-bound).  [R16, frozen]
__global__ __launch_bounds__(256) void fused_k(const float* __restrict__ x,
                                               const float* __restrict__ P,
                                               const float* __restrict__ Q,
                                               const float* __restrict__ S,
                                               unsigned short* __restrict__ xb,
                                               unsigned short* __restrict__ K2t) {
  __shared__ float ldsK[256 * 4];
  const int bid = blockIdx.x;
  const int t = threadIdx.x;

  if (bid >= 576) {                  // ---- cast x -> bf16 ----
    int i = (bid - 576) * 256 + t;
    const f32x4* xp = (const f32x4*)x;
    f32x4 a = xp[2 * i];
    f32x4 b = xp[2 * i + 1];
    bf16x8 o;
    o[0] = (short)f2bf(a[0]); o[1] = (short)f2bf(a[1]);
    o[2] = (short)f2bf(a[2]); o[3] = (short)f2bf(a[3]);
    o[4] = (short)f2bf(b[0]); o[5] = (short)f2bf(b[1]);
    o[6] = (short)f2bf(b[2]); o[7] = (short)f2bf(b[3]);
    ((bf16x8*)xb)[i] = o;
    return;
  }

  const int kk = bid / 64;           // 0..8
  const int f0 = (bid & 63) * 4;     // 0..252
  {                                  // phase 1: Keff slice -> LDS (thread = o)
    float k0 = 0.f, k1 = 0.f, k2 = 0.f, k3 = 0.f;
    const float* qp = Q + t * 144 + kk * 16;
    const float* sp = S + (t >> 4) * 4096 + (t & 15) * 256 + f0;
#pragma unroll
    for (int bi = 0; bi < 16; ++bi) {
      float qv = qp[bi];
      const float* s4 = sp + bi * 65536;
      k0 = fmaf(qv, s4[0], k0); k1 = fmaf(qv, s4[1], k1);
      k2 = fmaf(qv, s4[2], k2); k3 = fmaf(qv, s4[3], k3);
    }
    ldsK[t * 4 + 0] = k0; ldsK[t * 4 + 1] = k1;
    ldsK[t * 4 + 2] = k2; ldsK[t * 4 + 3] = k3;
  }
  __syncthreads();
  {                                  // phase 2: contraction over o (thread = ci)
    const int ci = t;
    float acc[4] = {0.f, 0.f, 0.f, 0.f};
#pragma unroll 8
    for (int o = 0; o < 256; ++o) {
      float pv = P[o * 256 + ci];
      acc[0] = fmaf(pv, ldsK[o * 4 + 0], acc[0]);
      acc[1] = fmaf(pv, ldsK[o * 4 + 1], acc[1]);
      acc[2] = fmaf(pv, ldsK[o * 4 + 2], acc[2]);
      acc[3] = fmaf(pv, ldsK[o * 4 + 3], acc[3]);
    }
#pragma unroll
    for (int j = 0; j < 4; ++j)
      K2t[kk * 65536 + (f0 + j) * 256 + ci] = f2bf(acc[j]);
  }
}

// ---- main: implicit-GEMM conv with A-WINDOW (L2-traffic cut).
// Block = 124 output pixels (2 rows; 3844 = 31*124) x BN=128. Window = 4 input
// rows x 64 w x 64 ch(cb) bf16 = 32KB, staged ONCE per cb from xb via
// global_load_lds (linear dest -> conflict-free), reused by all 9 taps:
// A L2-read 16KB/step -> 3.6KB/step. B: R12 path (2x16KB dbuf, 0-conflict
// swizzle). 64KB LDS -> 2 blocks/CU. R17 one-barrier ring. Window refill at
// kk==8: upfront reads -> lgkm(0)+barrier -> 8 gloads -> MFMAs cover latency.
// Grid 496 = 8 XCD x 62 exact; (nt=0,1) pair shares window within one XCD L2.
__global__ __launch_bounds__(256, 2) void conv_gemm(const unsigned short* __restrict__ xb,
                                                    const unsigned short* __restrict__ K2t,
                                                    float* __restrict__ out) {
  __shared__ __attribute__((aligned(16))) char smem[65536];
  // [0,32768): window; [32768,65536): B double-buffer (2 x 16KB)

  const int tid = threadIdx.x;
  const int lane = tid & 63;
  const int wid = tid >> 6;         // 0..3
  const int sk = wid >> 1;          // k-half (channels sk*32..+31 of cb)
  const int wn = wid & 1;           // n-half

  const int wgid = (blockIdx.x & 7) * 62 + (blockIdx.x >> 3);   // 496 = 8*62
  const int mt = wgid >> 1;         // 0..247
  const int nt = wgid & 1;
  const int bimg = mt / 31;
  const int rr2 = mt - bimg * 31;   // row-pair 0..30
  const int m_base = bimg * 3844 + rr2 * 124;
  const int xrow0 = bimg * 64 + rr2 * 2;   // global input row of window row 0
  const int n0 = nt * 128;

  const int rl = lane & 15;
  const int kg = lane >> 4;

  // ---- window staging: thread t owns 8 chunks j: site=(t>>3)+32j, slot=t&7.
  // dest linear: smem + j*4096 + t*16. source data-slot d=(t&7)^((t>>3)&7).
  int wA[8];
  {
    int d8 = ((tid & 7) ^ ((tid >> 3) & 7)) * 8;
#pragma unroll
    for (int j = 0; j < 8; ++j) {
      int row = xrow0 + (j >> 1);
      int w = (tid >> 3) + 32 * (j & 1);
      wA[j] = (row * 64 + w) * 256 + d8;
    }
  }

  // ---- B staging (R12 pattern) ----
  const int s_srcB = ((tid & 3) ^ ((tid >> 3) & 3)) * 8;
  const int fB0 = (n0 + (tid >> 2)) * 256 + s_srcB;
  const int fB1 = (n0 + (tid >> 2) + 64) * 256 + s_srcB;

  // ---- A read: per-mi window site base (lr = mi*16+rl clamped to 123)
  int s8[8];
#pragma unroll
  for (int mi = 0; mi < 8; ++mi) {
    int lr = mi * 16 + rl; if (lr > 123) lr = 123;
    int ho = (lr >= 62) ? 1 : 0;
    s8[mi] = ho * 64 + (lr - ho * 62);
  }
  const int csl = sk * 4 + kg;      // data 16B-slot (channel group) in 128B row

  // ---- B read offsets (R12) ----
  const int slotrB = (kg ^ ((rl >> 1) & 3)) * 16;
  const int boffR = sk * 8192 + (wn * 64 + rl) * 64 + slotrB;

  f32x4 zero = {0.f, 0.f, 0.f, 0.f};
  f32x4 acc[8][4];
#pragma unroll
  for (int i = 0; i < 8; ++i)
#pragma unroll
    for (int j = 0; j < 4; ++j) acc[i][j] = zero;

#define WSTAGE(cb)                                                             \
  {                                                                            \
    _Pragma("unroll")                                                          \
    for (int j = 0; j < 8; ++j)                                                \
      gload16(xb + wA[j] + (cb) * 64, smem + j * 4096 + tid * 16);             \
  }

#define STAGE_B(kk2, cb2, base)                                                \
  {                                                                            \
    int offB = (kk2) * 65536 + (cb2) * 64;                                     \
    unsigned short* bB = (unsigned short*)(base);                              \
    gload16(K2t + offB + fB0,      bB + tid * 8);                              \
    gload16(K2t + offB + fB1,      bB + (tid + 256) * 8);                      \
    gload16(K2t + offB + fB0 + 32, bB + (tid + 512) * 8);                      \
    gload16(K2t + offB + fB1 + 32, bB + (tid + 768) * 8);                      \
  }

#define AF_READ(dst, mi, koff)                                                 \
  {                                                                            \
    int st = s8[mi] + (koff);                                                  \
    dst = *(const bf16x8*)(smem + st * 128 + ((csl ^ (st & 7)) << 4));         \
  }

  // prologue: window cb=0 + B tile (0,0)
  WSTAGE(0);
  STAGE_B(0, 0, smem + 32768);
  asm volatile("s_waitcnt vmcnt(0)" ::: "memory");
  __builtin_amdgcn_sched_barrier(0);
  __builtin_amdgcn_s_barrier();
  __builtin_amdgcn_sched_barrier(0);

  int par = 0;                      // B-buffer parity of current step
  for (int cb = 0; cb < 4; ++cb) {
    for (int kk = 0; kk < 9; ++kk) {
      const int last = (cb == 3) && (kk == 8);
      char* curB = smem + 32768 + par * 16384;
      char* nxtB = smem + 32768 + (par ^ 1) * 16384;
      const int koff = (kk / 3) * 64 + (kk - (kk / 3) * 3);

      // 1) issue next B stage first
      if (!last) {
        if (kk < 8) {
          STAGE_B(kk + 1, cb, nxtB);
        } else {
          STAGE_B(0, cb + 1, nxtB);
        }
      }
      __builtin_amdgcn_sched_barrier(0);

      bf16x8 bfr[4];
#pragma unroll
      for (int ni = 0; ni < 4; ++ni)
        bfr[ni] = *(const bf16x8*)(curB + boffR + ni * 1024);

      if (kk == 8 && cb < 3) {
        // upfront reads; fence; refill window; MFMAs cover the gload latency
        bf16x8 af[8];
#pragma unroll
        for (int mi = 0; mi < 8; ++mi) AF_READ(af[mi], mi, koff);
        asm volatile("s_waitcnt lgkmcnt(0)" ::: "memory");
        __builtin_amdgcn_sched_barrier(0);
        __builtin_amdgcn_s_barrier();           // all waves done reading window
        __builtin_amdgcn_sched_barrier(0);
        WSTAGE(cb + 1);
        __builtin_amdgcn_sched_barrier(0);
        __builtin_amdgcn_s_setprio(1);
#pragma unroll
        for (int mi = 0; mi < 8; ++mi)
#pragma unroll
          for (int ni = 0; ni < 4; ++ni)
            acc[mi][ni] = __builtin_amdgcn_mfma_f32_16x16x32_bf16(
                af[mi], bfr[ni], acc[mi][ni], 0, 0, 0);
        __builtin_amdgcn_s_setprio(0);
      } else {
        // progressive body (R17)
        bf16x8 a0, a1;
        AF_READ(a0, 0, koff);
        AF_READ(a1, 1, koff);
#pragma unroll
        for (int j = 0; j < 4; ++j) {
          bf16x8 a2, a3;
          if (j < 3) {
            AF_READ(a2, 2 * j + 2, koff);
            AF_READ(a3, 2 * j + 3, koff);
          }
          __builtin_amdgcn_s_setprio(1);
#pragma unroll
          for (int ni = 0; ni < 4; ++ni)
            acc[2 * j][ni] = __builtin_amdgcn_mfma_f32_16x16x32_bf16(
                a0, bfr[ni], acc[2 * j][ni], 0, 0, 0);
#pragma unroll
          for (int ni = 0; ni < 4; ++ni)
            acc[2 * j + 1][ni] = __builtin_amdgcn_mfma_f32_16x16x32_bf16(
                a1, bfr[ni], acc[2 * j + 1][ni], 0, 0, 0);
          __builtin_amdgcn_s_setprio(0);
          a0 = a2; a1 = a3;
        }
      }

      // 3) end-of-step: drain stages (B next + window), sync
      if (!last) {
        __builtin_amdgcn_sched_barrier(0);
        asm volatile("s_waitcnt vmcnt(0)" ::: "memory");
        __builtin_amdgcn_sched_barrier(0);
        __builtin_amdgcn_s_barrier();
        __builtin_amdgcn_sched_barrier(0);
      }
      par ^= 1;
    }
  }

  __syncthreads();   // main loop done; smem reused as reduction buffer

  // epilogue: sk=1 stages acc in LDS (64KB exactly); sk=0 adds + stores.
  // D row-in-tile = mi*16 + kg*4 + r (<124 valid), col = rl + 16*ni + 64*wn.
  float* red = (float*)smem;
  if (sk == 1) {
#pragma unroll
    for (int mi = 0; mi < 8; ++mi)
#pragma unroll
      for (int ni = 0; ni < 4; ++ni)
        *(f32x4*)((char*)red + (((wn * 8 + mi) * 4 + ni) * 64 + lane) * 16) =
            acc[mi][ni];
  }
  __syncthreads();
  if (sk == 0) {
#pragma unroll
    for (int mi = 0; mi < 8; ++mi) {
#pragma unroll
      for (int ni = 0; ni < 4; ++ni) {
        f32x4 o = *(f32x4*)((char*)red + (((wn * 8 + mi) * 4 + ni) * 64 + lane) * 16);
        o += acc[mi][ni];
        int f = n0 + wn * 64 + ni * 16 + rl;
#pragma unroll
        for (int r = 0; r < 4; ++r) {
          int lrow = mi * 16 + kg * 4 + r;
          if (lrow < 124) out[(m_base + lrow) * 256 + f] = o[r];
        }
      }
    }
  }
#undef WSTAGE
#undef STAGE_B
#undef AF_READ
}

extern "C" void kernel_launch(void* const* d_in, const int* in_sizes, int n_in,
                              void* d_out, int out_size, void* d_ws, size_t ws_size,
                              hipStream_t stream) {
  const float* x = (const float*)d_in[0];   // [8,64,64,256]
  const float* P = (const float*)d_in[1];   // [256,256]
  const float* Q = (const float*)d_in[2];   // [256,3,3,16]
  const float* S = (const float*)d_in[3];   // [256,16,256]
  float* out = (float*)d_out;               // [8,62,62,256]

  char* ws = (char*)d_ws;
  unsigned short* xb  = (unsigned short*)ws;               // 16,777,216 B
  unsigned short* K2t = (unsigned short*)(ws + 16777216);  //  1,179,648 B

  fused_k<<<4672, 256, 0, stream>>>(x, P, Q, S, xb, K2t);
  conv_gemm<<<496, 256, 0, stream>>>(xb, K2t, out);
}